// Round 1
// baseline (2868.257 us; speedup 1.0000x reference)
//
#include <hip/hip_runtime.h>
#include <hip/hip_bf16.h>

// Problem constants
#define B_ 8
#define T_ 1024
#define E_ 768
#define H_ 12
#define DH_ 64
#define E3_ 2304
#define M_ (B_ * T_)           // 8192 rows
#define SCALE_ 0.125f          // 64^-0.5

// ---------------------------------------------------------------------------
// Tiled fp32 GEMM + bias: C[M,N] = A[M,K] @ W[K,N] + bias[N]
// BM=BN=64, BK=16, 256 threads (16x16), 4x4 microtile per thread.
// M,N,K all divisible by tile dims for our shapes (no bounds checks).
// ---------------------------------------------------------------------------
#define BM 64
#define BN 64
#define BK 16
__global__ __launch_bounds__(256) void gemm_bias(const float* __restrict__ A,
                                                 const float* __restrict__ W,
                                                 const float* __restrict__ bias,
                                                 float* __restrict__ C,
                                                 int M, int N, int K) {
    __shared__ float As[BK][BM + 1];
    __shared__ float Ws[BK][BN + 1];

    const int tid = threadIdx.x;
    const int tx = tid & 15;        // 0..15 -> N dir
    const int ty = tid >> 4;        // 0..15 -> M dir
    const int bm = blockIdx.y * BM;
    const int bn = blockIdx.x * BN;

    float acc[4][4] = {};

    for (int k0 = 0; k0 < K; k0 += BK) {
        // load A tile: 64 rows x 16 k  (each thread: 4 elems)
        for (int i = tid; i < BM * BK; i += 256) {
            int m = i >> 4;          // i / BK
            int kk = i & 15;         // i % BK
            As[kk][m] = A[(size_t)(bm + m) * K + k0 + kk];
        }
        // load W tile: 16 k x 64 n (coalesced over n)
        for (int i = tid; i < BK * BN; i += 256) {
            int kk = i >> 6;         // i / BN
            int n = i & 63;          // i % BN
            Ws[kk][n] = W[(size_t)(k0 + kk) * N + bn + n];
        }
        __syncthreads();

#pragma unroll
        for (int kk = 0; kk < BK; ++kk) {
            float a[4], w[4];
#pragma unroll
            for (int i = 0; i < 4; ++i) a[i] = As[kk][ty * 4 + i];
#pragma unroll
            for (int j = 0; j < 4; ++j) w[j] = Ws[kk][tx * 4 + j];
#pragma unroll
            for (int i = 0; i < 4; ++i)
#pragma unroll
                for (int j = 0; j < 4; ++j) acc[i][j] += a[i] * w[j];
        }
        __syncthreads();
    }

#pragma unroll
    for (int i = 0; i < 4; ++i) {
        int row = bm + ty * 4 + i;
#pragma unroll
        for (int j = 0; j < 4; ++j) {
            int col = bn + tx * 4 + j;
            C[(size_t)row * N + col] = acc[i][j] + bias[col];
        }
    }
}

// ---------------------------------------------------------------------------
// Flash-style attention. mixed is [B*T, 2304] with Q at col h*64, K at
// 768 + h*64, V at 1536 + h*64. One block per (b,h,q-tile of 32 rows).
// Online softmax over K/V tiles of 32. O accumulator in registers:
// thread t owns row r = t>>3, dims d0=(t&7)*8 .. +8.
// Output ctx is [B*T, 768] with head h at col h*64 (i.e. [B,T,H,Dh]).
// ---------------------------------------------------------------------------
__global__ __launch_bounds__(256) void attn_flash(const float* __restrict__ mixed,
                                                  float* __restrict__ ctx) {
    const int bh = blockIdx.y;
    const int b = bh / H_;
    const int h = bh % H_;
    const int q0 = blockIdx.x * 32;
    const int t = threadIdx.x;

    __shared__ float Qs[32][64];
    __shared__ float Ks[32][65];
    __shared__ float Vs[32][64];
    __shared__ float Ss[32][33];
    __shared__ float m_s[32], l_s[32], alpha_s[32];

    const size_t qbase = ((size_t)(b * T_ + q0)) * E3_ + h * DH_;
    // load Q tile (stays resident)
    for (int i = t; i < 32 * 64; i += 256) {
        int r = i >> 6, d = i & 63;
        Qs[r][d] = mixed[qbase + (size_t)r * E3_ + d];
    }
    if (t < 32) { m_s[t] = -1e30f; l_s[t] = 0.0f; }
    __syncthreads();

    const int r = t >> 3;            // my O row
    const int d0 = (t & 7) * 8;      // my O dim base
    float acc[8] = {};

    const size_t kbase = ((size_t)(b * T_)) * E3_ + 768 + h * DH_;
    const size_t vbase = ((size_t)(b * T_)) * E3_ + 1536 + h * DH_;

    for (int kv0 = 0; kv0 < T_; kv0 += 32) {
        // load K/V tiles
        for (int i = t; i < 32 * 64; i += 256) {
            int j = i >> 6, d = i & 63;
            Ks[j][d] = mixed[kbase + (size_t)(kv0 + j) * E3_ + d];
            Vs[j][d] = mixed[vbase + (size_t)(kv0 + j) * E3_ + d];
        }
        __syncthreads();

        // S tile: thread computes S[i=t>>3][jb..jb+3], jb=(t&7)*4
        {
            const int si = t >> 3;
            const int jb = (t & 7) * 4;
#pragma unroll
            for (int jj = 0; jj < 4; ++jj) {
                float s = 0.0f;
#pragma unroll
                for (int d = 0; d < 64; ++d) s += Qs[si][d] * Ks[jb + jj][d];
                Ss[si][jb + jj] = s * SCALE_;
            }
        }
        __syncthreads();

        // online softmax per row (32 threads, one row each)
        if (t < 32) {
            float mold = m_s[t];
            float mnew = mold;
#pragma unroll
            for (int j = 0; j < 32; ++j) mnew = fmaxf(mnew, Ss[t][j]);
            float al = __expf(mold - mnew);
            float sum = 0.0f;
#pragma unroll
            for (int j = 0; j < 32; ++j) {
                float p = __expf(Ss[t][j] - mnew);
                Ss[t][j] = p;
                sum += p;
            }
            l_s[t] = l_s[t] * al + sum;
            m_s[t] = mnew;
            alpha_s[t] = al;
        }
        __syncthreads();

        // rescale + accumulate O
        float al = alpha_s[r];
#pragma unroll
        for (int u = 0; u < 8; ++u) acc[u] *= al;
        for (int j = 0; j < 32; ++j) {
            float p = Ss[r][j];
#pragma unroll
            for (int u = 0; u < 8; ++u) acc[u] += p * Vs[j][d0 + u];
        }
        __syncthreads();
    }

    float inv = 1.0f / l_s[r];
    const size_t obase = ((size_t)(b * T_ + q0 + r)) * E_ + h * DH_ + d0;
#pragma unroll
    for (int u = 0; u < 8; ++u) ctx[obase + u] = acc[u] * inv;
}

// ---------------------------------------------------------------------------
extern "C" void kernel_launch(void* const* d_in, const int* in_sizes, int n_in,
                              void* d_out, int out_size, void* d_ws, size_t ws_size,
                              hipStream_t stream) {
    const float* hs     = (const float*)d_in[0];
    const float* qkv_w  = (const float*)d_in[1];
    const float* qkv_b  = (const float*)d_in[2];
    const float* proj_w = (const float*)d_in[3];
    const float* proj_b = (const float*)d_in[4];
    float* out = (float*)d_out;

    float* mixed = (float*)d_ws;                         // [8192, 2304]
    float* ctx   = mixed + (size_t)M_ * E3_;             // [8192, 768]

    // 1) QKV projection
    gemm_bias<<<dim3(E3_ / BN, M_ / BM), 256, 0, stream>>>(hs, qkv_w, qkv_b, mixed,
                                                           M_, E3_, E_);
    // 2) attention
    attn_flash<<<dim3(T_ / 32, B_ * H_), 256, 0, stream>>>(mixed, ctx);
    // 3) output projection
    gemm_bias<<<dim3(E_ / BN, M_ / BM), 256, 0, stream>>>(ctx, proj_w, proj_b, out,
                                                          M_, E_, E_);
}

// Round 2
// 256.324 us; speedup vs baseline: 11.1900x; 11.1900x over previous
//
#include <hip/hip_runtime.h>
#include <hip/hip_bf16.h>

// Problem constants
#define B_ 8
#define T_ 1024
#define E_ 768
#define H_ 12
#define DH_ 64
#define E3_ 2304
#define M_ (B_ * T_)           // 8192 rows
#define SCALE_ 0.125f          // 64^-0.5

typedef __attribute__((ext_vector_type(8))) short short8;
typedef __attribute__((ext_vector_type(4))) float float4_;
typedef __attribute__((ext_vector_type(4))) unsigned short ushort4_;

__device__ __forceinline__ unsigned short f2bf(float f) {
    union { float f; unsigned int u; } v; v.f = f;
    unsigned int r = v.u + 0x7fffu + ((v.u >> 16) & 1u);
    return (unsigned short)(r >> 16);
}

// ---------------------------------------------------------------------------
// fp32 -> bf16 elementwise cast (vectorized). n must be multiple of 4.
// ---------------------------------------------------------------------------
__global__ __launch_bounds__(256) void conv_f32_bf16(const float* __restrict__ x,
                                                     unsigned short* __restrict__ y,
                                                     int n) {
    int i = (blockIdx.x * 256 + threadIdx.x) * 4;
    int stride = gridDim.x * 256 * 4;
    for (; i < n; i += stride) {
        float4_ v = *(const float4_*)(x + i);
        ushort4_ o;
        o.x = f2bf(v.x); o.y = f2bf(v.y); o.z = f2bf(v.z); o.w = f2bf(v.w);
        *(ushort4_*)(y + i) = o;
    }
}

// ---------------------------------------------------------------------------
// W[K][N] fp32 -> Wt[N][K] bf16, tiled 32x32 transpose.
// ---------------------------------------------------------------------------
__global__ __launch_bounds__(256) void transpose_bf16(const float* __restrict__ W,
                                                      unsigned short* __restrict__ Wt,
                                                      int K, int N) {
    __shared__ float tile[32][33];
    const int k0 = blockIdx.y * 32, n0 = blockIdx.x * 32;
    const int tx = threadIdx.x & 31, ty = threadIdx.x >> 5;  // 8 rows/pass
    for (int i = ty; i < 32; i += 8)
        tile[i][tx] = W[(size_t)(k0 + i) * N + n0 + tx];
    __syncthreads();
    for (int i = ty; i < 32; i += 8)
        Wt[(size_t)(n0 + i) * K + k0 + tx] = f2bf(tile[tx][i]);
}

// ---------------------------------------------------------------------------
// bf16 MFMA GEMM: C[M,N] = A[M,K] @ Wt[N,K]^T + bias[N]
// Block: 256 thr (4 waves), tile 128x128, BK=32. Wave w: 64x64 quadrant,
// 4x4 grid of 16x16x32 MFMA tiles.
// LDS k-plane layout: plane kc (k-chunk of 8 elems): [128 rows][8 elems],
// plane stride 1040 elems (2080 B) -> conflict-free staging + frag reads.
// STORE_BF16: 1 -> write bf16 (u16), 0 -> write fp32.
// ---------------------------------------------------------------------------
template <int STORE_BF16>
__global__ __launch_bounds__(256) void gemm_mfma(const unsigned short* __restrict__ A,
                                                 const unsigned short* __restrict__ Wt,
                                                 const float* __restrict__ bias,
                                                 void* __restrict__ Cout,
                                                 int M, int N, int K) {
    __shared__ unsigned short Al[4 * 1040];
    __shared__ unsigned short Wl[4 * 1040];

    const int tid = threadIdx.x;
    const int lane = tid & 63;
    const int wid = tid >> 6;
    const int bm = blockIdx.y * 128;
    const int bn = blockIdx.x * 128;
    const int wm = (wid >> 1) * 64;
    const int wn = (wid & 1) * 64;
    const int quad = lane >> 4;
    const int l16 = lane & 15;

    // staging: slot s in [0,512): row = s>>2, kc = s&3; this thread: s=tid, tid+256
    const int r0 = tid >> 2;      // 0..63
    const int kc0 = tid & 3;

    float4_ acc[4][4] = {};

    for (int k0 = 0; k0 < K; k0 += 32) {
        short8 a1 = *(const short8*)(A + (size_t)(bm + r0) * K + k0 + kc0 * 8);
        short8 a2 = *(const short8*)(A + (size_t)(bm + r0 + 64) * K + k0 + kc0 * 8);
        short8 w1 = *(const short8*)(Wt + (size_t)(bn + r0) * K + k0 + kc0 * 8);
        short8 w2 = *(const short8*)(Wt + (size_t)(bn + r0 + 64) * K + k0 + kc0 * 8);
        __syncthreads();
        *(short8*)(&Al[kc0 * 1040 + r0 * 8]) = a1;
        *(short8*)(&Al[kc0 * 1040 + (r0 + 64) * 8]) = a2;
        *(short8*)(&Wl[kc0 * 1040 + r0 * 8]) = w1;
        *(short8*)(&Wl[kc0 * 1040 + (r0 + 64) * 8]) = w2;
        __syncthreads();

        short8 af[4], bf[4];
#pragma unroll
        for (int mt = 0; mt < 4; ++mt)
            af[mt] = *(const short8*)(&Al[quad * 1040 + (wm + mt * 16 + l16) * 8]);
#pragma unroll
        for (int nt = 0; nt < 4; ++nt)
            bf[nt] = *(const short8*)(&Wl[quad * 1040 + (wn + nt * 16 + l16) * 8]);
#pragma unroll
        for (int mt = 0; mt < 4; ++mt)
#pragma unroll
            for (int nt = 0; nt < 4; ++nt)
                acc[mt][nt] = __builtin_amdgcn_mfma_f32_16x16x32_bf16(af[mt], bf[nt],
                                                                      acc[mt][nt], 0, 0, 0);
    }

    // epilogue: C[row = quad*4+i][col = lane&15] per 16x16 tile
#pragma unroll
    for (int nt = 0; nt < 4; ++nt) {
        const int col = bn + wn + nt * 16 + l16;
        const float bv = bias[col];
#pragma unroll
        for (int mt = 0; mt < 4; ++mt) {
#pragma unroll
            for (int i = 0; i < 4; ++i) {
                const int row = bm + wm + mt * 16 + quad * 4 + i;
                const float v = acc[mt][nt][i] + bv;
                if (STORE_BF16)
                    ((unsigned short*)Cout)[(size_t)row * N + col] = f2bf(v);
                else
                    ((float*)Cout)[(size_t)row * N + col] = v;
            }
        }
    }
}

// ---------------------------------------------------------------------------
// MFMA flash attention. mixed: [B*T][2304] bf16 (Q at h*64, K at 768+h*64,
// V at 1536+h*64). Block = (b, h, 64 q-rows); wave w owns q-rows w*16..+15.
// KV tiles of 64. Q frags in regs; K in LDS natural [key][d] (k-plane layout);
// V in LDS transposed Vt[d][key]; P round-trips C-layout -> A-layout via
// per-wave LDS. Online softmax per q-row via shfl over 16-lane col groups.
// Output ctx [B*T][768] bf16 (head h at col h*64).
// ---------------------------------------------------------------------------
__global__ __launch_bounds__(256) void attn_mfma(const unsigned short* __restrict__ mixed,
                                                 unsigned short* __restrict__ ctx) {
    const int bh = blockIdx.y;
    const int b = bh / H_;
    const int h = bh % H_;
    const int q0 = blockIdx.x * 64;
    const int tid = threadIdx.x;
    const int lane = tid & 63;
    const int wid = tid >> 6;
    const int quad = lane >> 4;
    const int l16 = lane & 15;

    // K planes: kc in [0,8): [64 keys][8 elems], plane stride 520 elems (1040B)
    __shared__ unsigned short Kl[8 * 520];
    // Vt planes: key-chunk kk in [0,8): [64 d][8 keys], plane stride 520
    __shared__ unsigned short Vt[8 * 520];
    // per-wave P: [16 q][64 key], row stride 72 elems (16B-aligned rows)
    __shared__ unsigned short Pl[4][16 * 72];

    // Q fragments (A-operand, 2 k-steps over d=64)
    short8 qf[2];
    {
        const size_t qrow = (size_t)(b * T_ + q0 + wid * 16 + l16) * E3_ + h * 64;
        qf[0] = *(const short8*)(mixed + qrow + quad * 8);
        qf[1] = *(const short8*)(mixed + qrow + 32 + quad * 8);
    }

    float4_ o[4] = {};               // O C-frags over 4 d-tiles
    float m_i[4], l_i[4];
#pragma unroll
    for (int i = 0; i < 4; ++i) { m_i[i] = -1e30f; l_i[i] = 0.0f; }

    const size_t kbase = (size_t)(b * T_) * E3_ + E_ + h * 64;
    const size_t vbase = (size_t)(b * T_) * E3_ + 2 * E_ + h * 64;

    // K staging: slot s: key = s>>3 (0..63 over 2 slots), kc = s&7
    const int sk_key = tid >> 3;     // 0..31 (+32 second slot)
    const int sk_kc = tid & 7;
    // V staging: thread t: key = lane, d-chunk = wid (+4 second slot)
    const int sv_key = lane;
    const int sv_kk = sv_key >> 3;
    const int sv_k7 = sv_key & 7;

    for (int kv0 = 0; kv0 < T_; kv0 += 64) {
        short8 kv1 = *(const short8*)(mixed + kbase + (size_t)(kv0 + sk_key) * E3_ + sk_kc * 8);
        short8 kv2 = *(const short8*)(mixed + kbase + (size_t)(kv0 + sk_key + 32) * E3_ + sk_kc * 8);
        short8 vv1 = *(const short8*)(mixed + vbase + (size_t)(kv0 + sv_key) * E3_ + wid * 8);
        short8 vv2 = *(const short8*)(mixed + vbase + (size_t)(kv0 + sv_key) * E3_ + (wid + 4) * 8);
        __syncthreads();
        *(short8*)(&Kl[sk_kc * 520 + sk_key * 8]) = kv1;
        *(short8*)(&Kl[sk_kc * 520 + (sk_key + 32) * 8]) = kv2;
        {
            const unsigned short* p1 = (const unsigned short*)&vv1;
            const unsigned short* p2 = (const unsigned short*)&vv2;
#pragma unroll
            for (int j = 0; j < 8; ++j)
                Vt[sv_kk * 520 + (wid * 8 + j) * 8 + sv_k7] = p1[j];
#pragma unroll
            for (int j = 0; j < 8; ++j)
                Vt[sv_kk * 520 + ((wid + 4) * 8 + j) * 8 + sv_k7] = p2[j];
        }
        __syncthreads();

        // S = Q K^T over 4 key-tiles of 16
        float4_ s[4];
#pragma unroll
        for (int nt = 0; nt < 4; ++nt) {
            const int key = nt * 16 + l16;
            short8 kf0 = *(const short8*)(&Kl[quad * 520 + key * 8]);
            short8 kf1 = *(const short8*)(&Kl[(4 + quad) * 520 + key * 8]);
            float4_ z = {};
            z = __builtin_amdgcn_mfma_f32_16x16x32_bf16(qf[0], kf0, z, 0, 0, 0);
            s[nt] = __builtin_amdgcn_mfma_f32_16x16x32_bf16(qf[1], kf1, z, 0, 0, 0);
        }
#pragma unroll
        for (int nt = 0; nt < 4; ++nt) s[nt] *= SCALE_;

        // online softmax per row r = quad*4+i (cols spread over 16-lane group)
        float alpha[4];
#pragma unroll
        for (int i = 0; i < 4; ++i) {
            float mx = fmaxf(fmaxf(s[0][i], s[1][i]), fmaxf(s[2][i], s[3][i]));
#pragma unroll
            for (int msk = 1; msk < 16; msk <<= 1) mx = fmaxf(mx, __shfl_xor(mx, msk, 64));
            const float mnew = fmaxf(m_i[i], mx);
            alpha[i] = __expf(m_i[i] - mnew);
            m_i[i] = mnew;
            float sum = 0.0f;
#pragma unroll
            for (int nt = 0; nt < 4; ++nt) {
                const float p = __expf(s[nt][i] - mnew);
                s[nt][i] = p;
                sum += p;
            }
#pragma unroll
            for (int msk = 1; msk < 16; msk <<= 1) sum += __shfl_xor(sum, msk, 64);
            l_i[i] = l_i[i] * alpha[i] + sum;
        }

        // P: C-layout -> LDS -> A-layout (per-wave region, in-wave DS ordering)
        unsigned short* pw = &Pl[wid][0];
#pragma unroll
        for (int nt = 0; nt < 4; ++nt)
#pragma unroll
            for (int i = 0; i < 4; ++i)
                pw[(quad * 4 + i) * 72 + nt * 16 + l16] = f2bf(s[nt][i]);

#pragma unroll
        for (int dt = 0; dt < 4; ++dt)
#pragma unroll
            for (int i = 0; i < 4; ++i) o[dt][i] *= alpha[i];

        short8 pf0 = *(const short8*)(&pw[l16 * 72 + quad * 8]);
        short8 pf1 = *(const short8*)(&pw[l16 * 72 + 32 + quad * 8]);
#pragma unroll
        for (int dt = 0; dt < 4; ++dt) {
            const int d = dt * 16 + l16;
            short8 vf0 = *(const short8*)(&Vt[quad * 520 + d * 8]);
            short8 vf1 = *(const short8*)(&Vt[(4 + quad) * 520 + d * 8]);
            o[dt] = __builtin_amdgcn_mfma_f32_16x16x32_bf16(pf0, vf0, o[dt], 0, 0, 0);
            o[dt] = __builtin_amdgcn_mfma_f32_16x16x32_bf16(pf1, vf1, o[dt], 0, 0, 0);
        }
    }

    // final normalize + store ctx (bf16)
#pragma unroll
    for (int dt = 0; dt < 4; ++dt) {
#pragma unroll
        for (int i = 0; i < 4; ++i) {
            const float v = o[dt][i] / l_i[i];
            const size_t row = (size_t)(b * T_ + q0 + wid * 16 + quad * 4 + i);
            ctx[row * E_ + h * 64 + dt * 16 + l16] = f2bf(v);
        }
    }
}

// ---------------------------------------------------------------------------
extern "C" void kernel_launch(void* const* d_in, const int* in_sizes, int n_in,
                              void* d_out, int out_size, void* d_ws, size_t ws_size,
                              hipStream_t stream) {
    const float* hs     = (const float*)d_in[0];
    const float* qkv_w  = (const float*)d_in[1];
    const float* qkv_b  = (const float*)d_in[2];
    const float* proj_w = (const float*)d_in[3];
    const float* proj_b = (const float*)d_in[4];
    float* out = (float*)d_out;

    unsigned short* hs_bf  = (unsigned short*)d_ws;                 // [8192][768]
    unsigned short* qkvwT  = hs_bf + (size_t)M_ * E_;               // [2304][768]
    unsigned short* projwT = qkvwT + (size_t)E3_ * E_;              // [768][768]
    unsigned short* mixed  = projwT + (size_t)E_ * E_;              // [8192][2304]
    unsigned short* ctx    = mixed + (size_t)M_ * E3_;              // [8192][768]

    // casts / weight transposes
    conv_f32_bf16<<<6144, 256, 0, stream>>>(hs, hs_bf, M_ * E_);
    transpose_bf16<<<dim3(E3_ / 32, E_ / 32), 256, 0, stream>>>(qkv_w, qkvwT, E_, E3_);
    transpose_bf16<<<dim3(E_ / 32, E_ / 32), 256, 0, stream>>>(proj_w, projwT, E_, E_);

    // 1) QKV projection -> mixed (bf16)
    gemm_mfma<1><<<dim3(E3_ / 128, M_ / 128), 256, 0, stream>>>(hs_bf, qkvwT, qkv_b,
                                                                (void*)mixed, M_, E3_, E_);
    // 2) attention -> ctx (bf16)
    attn_mfma<<<dim3(T_ / 64, B_ * H_), 256, 0, stream>>>(mixed, ctx);
    // 3) output projection -> out (fp32)
    gemm_mfma<0><<<dim3(E_ / 128, M_ / 128), 256, 0, stream>>>(ctx, projwT, proj_b,
                                                               (void*)out, M_, E_, E_);
}